// Round 12
// baseline (83.595 us; speedup 1.0000x reference)
//
#include <hip/hip_runtime.h>

// SpikingConv2D: y = conv3x3_same(tj, W) + (1 - D_i[0,f]); out = min(y, 1.0), NHWC fp32.
// R11: FUSED single main kernel -- the NCHW f32 -> padded-NHWC bf16 conversion happens
// inside the conv kernel (per-wave, barrier-free), eliminating the 27.5 MB xp
// intermediate (prep_x write + main re-read) and one dispatch.
//  - Base = R6 (proven race-free minimal-sync): block = 4 rows x 56 px x 128 f,
//    4 waves (7M x 4N frags), grid 448 XCD-bijective, A patch quarter double-buffer,
//    barriers ONLY at quarter ends, B from L2-resident Wt register parity pipeline.
//  - In-kernel transpose, per wave (wave wv owns channel octet wv of the quarter):
//    unit = one patch row x 8 ch: (1) coalesced f32 reads from x: lane (cl=l>>3,
//    pg=l&7) reads 7 floats of channel cl at w=pg*7..+6; (2) store to per-wave 2 KB
//    LDS scratch f32 [w][8] (stride 8 words: b128-aligned reads, 2-way conflicts);
//    (3) lane p packs granule (8 ch of pixel slot p) -> f2bf -> swizzled
//    ds_write_b128 into patch[(q+1)&1]. Wave-local scratch => no extra barriers;
//    patch visibility via the existing quarter-end __syncthreads. 6 units per wave
//    per quarter, spread over taps r=1..6.
//  - ds_write can scatter, so swz() applies directly on the write (the
//    global_load_lds linear-dest constraint is gone along with global_load_lds).

#define BZ 32
#define CC 128
#define HH 56
#define WWD 56
#define HWP 3136
#define FF 128
#define PH 58
#define PW 58
#define AB_BYTES 24576      // per A buffer: 1536 granules * 16 B (1392 real)
#define SCR_OFF 49152       // per-wave f32 transpose scratch: 4 x 2048 B
#define SCR_WAVE 2048
#define LDS_TOTAL 57344
#define NSTEP 36

typedef __attribute__((ext_vector_type(8))) __bf16 bf16x8;
typedef __attribute__((ext_vector_type(4))) float f32x4;
typedef __attribute__((ext_vector_type(8))) unsigned short us8;
typedef __attribute__((ext_vector_type(4))) float flt4;

__device__ __forceinline__ unsigned short f2bf(float f) {
  unsigned int u = __float_as_uint(f);
  unsigned int r = (u + 0x7FFFu + ((u >> 16) & 1u)) >> 16;
  return (unsigned short)r;
}

__device__ __forceinline__ int swz(int g) { return g ^ ((g >> 3) & 3); }

// ---- W repack (linear): Wt slice S=q*9+r, granule g=f*4+kg holds channels
//      q*32+kg*8..+8 of filter f, tap r. 512 granules (8 KB) per slice. ----
__global__ void prep_w_kernel(const float* __restrict__ W, unsigned short* __restrict__ Wt) {
  int idx = blockIdx.x * 256 + threadIdx.x;
  if (idx >= NSTEP * 512) return;
  int qr = idx >> 9;
  int g = idx & 511;
  int q = qr / 9, r = qr - q * 9;
  int f = g >> 2, kg = g & 3;
  us8 v;
#pragma unroll
  for (int j = 0; j < 8; ++j) {
    int c = q * 32 + kg * 8 + j;
    v[j] = f2bf(W[(c * 9 + r) * FF + f]);
  }
  *reinterpret_cast<us8*>(Wt + (size_t)idx * 8) = v;
}

// ---------------- main kernel ----------------
struct Ctx {
  const float* x;
  const unsigned short* Wt;
  int b, h0;
  int lane, wv;
  int gbase[7];         // A-frag logical granule (dh=dw=0) per M-frag
  int gB[4];            // B element offsets within a slice (j=0..3)
  f32x4 acc[7][4];
  bf16x8 bb[2][4];      // B-frag double buffer (parity = slice index & 1)
};

// One transpose unit: patch row u (0..5) x channel octet wv of quarter tq.
// Wave-local (scratch handoff + lgkm ordering); patch visibility via quarter barrier.
__device__ __forceinline__ void unit(Ctx& c, unsigned char* lds, int tq, int bufpar, int u) {
  const int cl = c.lane >> 3;   // channel within octet (0..7)
  const int pg = c.lane & 7;    // pixel group (7 px each)
  const int h = c.h0 + u - 1;   // image row of patch row u
  const bool rowok = ((unsigned)h < (unsigned)HH);

  float* scr = reinterpret_cast<float*>(lds + SCR_OFF + c.wv * SCR_WAVE);

  // (1) coalesced f32 reads: 7 consecutive w of one channel row
  float v[7];
  const float* src =
      c.x + ((size_t)(c.b * CC + tq * 32 + c.wv * 8 + cl)) * HWP + h * WWD + pg * 7;
#pragma unroll
  for (int t = 0; t < 7; ++t) v[t] = rowok ? src[t] : 0.0f;
  // (2) scratch transpose store: f32 [w][8ch], stride 8 words (b128-aligned reads)
#pragma unroll
  for (int t = 0; t < 7; ++t) scr[(pg * 7 + t) * 8 + cl] = v[t];
  // compiler inserts the wave-local lgkm wait between these ds ops
  // (3) pack granule p (8 ch of pixel slot p; w = p-1, slots 0 and 57 are pad)
  const int p = c.lane;
  if (p < 58) {
    us8 g;
    const bool gz = !rowok || p == 0 || p == 57;
    if (gz) {
#pragma unroll
      for (int j = 0; j < 8; ++j) g[j] = 0;
    } else {
      flt4 a = *reinterpret_cast<const flt4*>(scr + (p - 1) * 8);
      flt4 b2 = *reinterpret_cast<const flt4*>(scr + (p - 1) * 8 + 4);
#pragma unroll
      for (int j = 0; j < 4; ++j) g[j] = f2bf(a[j]);
#pragma unroll
      for (int j = 0; j < 4; ++j) g[4 + j] = f2bf(b2[j]);
    }
    const int gi = u * 232 + p * 4 + c.wv;  // logical granule (row, px, octet)
    *reinterpret_cast<us8*>(lds + bufpar * AB_BYTES + (swz(gi) << 4)) = g;
  }
}

template <int S>
__device__ __forceinline__ void step(Ctx& c, unsigned char* lds) {
  constexpr int q = S / 9, r = S - q * 9;
  const unsigned char* pa = lds + (q & 1) * AB_BYTES;

  // B prefetch for tap S+1 (global, L2-resident)
  if constexpr (S + 1 < NSTEP) {
    const unsigned short* ws = c.Wt + (size_t)(S + 1) * 4096;
#pragma unroll
    for (int j = 0; j < 4; ++j)
      c.bb[(S + 1) & 1][j] = *reinterpret_cast<const bf16x8*>(ws + c.gB[j]);
  }
  // in-kernel conversion of next quarter's patch, one unit per tap r=1..6
  if constexpr (r >= 1 && r <= 6 && q < 3) {
    unit(c, lds, q + 1, (q + 1) & 1, r - 1);
  }

  // A-frags for THIS tap
  constexpr int dh = r / 3 - 1, dw = r - (r / 3) * 3 - 1;
  constexpr int tapoff = (dh * PW + dw) * 4;  // logical granules
  bf16x8 af[7];
#pragma unroll
  for (int i = 0; i < 7; ++i) {
    int gt = c.gbase[i] + tapoff;
    af[i] = *reinterpret_cast<const bf16x8*>(pa + (swz(gt) << 4));
  }

  // 28-MFMA cluster
#pragma unroll
  for (int i = 0; i < 7; ++i)
#pragma unroll
    for (int j = 0; j < 4; ++j)
      c.acc[i][j] =
          __builtin_amdgcn_mfma_f32_16x16x32_bf16(af[i], c.bb[S & 1][j], c.acc[i][j], 0, 0, 0);

  // quarter-end: drain + barrier makes next quarter's patch visible to all waves.
  if constexpr (r == 8 && q < 3) __syncthreads();
}

template <int S>
__device__ __forceinline__ void do_steps(Ctx& c, unsigned char* lds) {
  step<S>(c, lds);
  if constexpr (S + 1 < NSTEP) do_steps<S + 1>(c, lds);
}

__global__ __launch_bounds__(256, 2) void spiking_conv_main(
    const float* __restrict__ x, const unsigned short* __restrict__ Wt,
    const float* __restrict__ Di, float* __restrict__ out) {
  __shared__ unsigned char lds[LDS_TOTAL];  // 48 KB patch dbuf + 8 KB wave scratch

  const int bid = blockIdx.x;
  const int wg = (bid & 7) * 56 + (bid >> 3);  // 448 = 56 per XCD, bijective
  const int b = wg / 14;
  const int rg = wg - b * 14;
  const int h0 = rg * 4;

  Ctx c;
  c.x = x;
  c.Wt = Wt;
  c.b = b;
  c.h0 = h0;
  const int tid = threadIdx.x;
  const int lane = tid & 63, wv = tid >> 6;
  c.lane = lane;
  c.wv = wv;
  const int wr = wv >> 1, wc = wv & 1;
  const int frow = lane & 15, kg = lane >> 4;

#pragma unroll
  for (int i = 0; i < 7; ++i) {
    int t = 16 * i + frow;  // 0..111 within wave's 112-px half
    int rowb = (t >= 56) ? 1 : 0;
    int col = t - 56 * rowb;
    c.gbase[i] = ((2 * wr + rowb + 1) * PW + (col + 1)) * 4 + kg;
  }
#pragma unroll
  for (int j = 0; j < 4; ++j)
    c.gB[j] = ((wc * 64 + 16 * j + frow) * 4 + kg) * 8;

  const f32x4 zero = {0.0f, 0.0f, 0.0f, 0.0f};
#pragma unroll
  for (int i = 0; i < 7; ++i)
#pragma unroll
    for (int j = 0; j < 4; ++j) c.acc[i][j] = zero;

  // prologue: convert quarter 0 -> buf 0 (6 units), B slice 0 -> bb[0], barrier.
#pragma unroll
  for (int u = 0; u < 6; ++u) unit(c, lds, 0, 0, u);
#pragma unroll
  for (int j = 0; j < 4; ++j)
    c.bb[0][j] = *reinterpret_cast<const bf16x8*>(Wt + c.gB[j]);
  __syncthreads();  // all waves' patch writes visible before any frag read

  do_steps<0>(c, lds);

  // epilogue: + (1 - D_i[f]), clamp 1.0, NHWC fp32
#pragma unroll
  for (int j = 0; j < 4; ++j) {
    const int col = wc * 64 + 16 * j + frow;
    const float thr = 1.0f - Di[col];
#pragma unroll
    for (int i = 0; i < 7; ++i) {
      const int bt = 16 * i + kg * 4;  // 4-run never crosses the 56 boundary
      const int rowb = (bt >= 56) ? 1 : 0;
      const int wl0 = bt - 56 * rowb;
      const int orow = h0 + 2 * wr + rowb;
      const size_t obase = ((size_t)b * HWP + (size_t)orow * WWD + wl0) * FF + col;
#pragma unroll
      for (int qq = 0; qq < 4; ++qq) {
        float v = c.acc[i][j][qq] + thr;
        out[obase + (size_t)qq * FF] = fminf(v, 1.0f);
      }
    }
  }
}

// ---- fallback (round-0 style, reads W directly; used only if ws too small) ----
__global__ __launch_bounds__(256) void spiking_conv_fallback(
    const float* __restrict__ x, const float* __restrict__ Wf,
    const float* __restrict__ Di, float* __restrict__ out) {
  __shared__ unsigned short Asm2[128][32];
  __shared__ unsigned short Bsm2[128][32];
  const int tid = threadIdx.x;
  const int m0 = blockIdx.x * 128;
  const int mi = tid & 127;
  const int half = tid >> 7;
  const int m = m0 + mi;
  const int bimg = m / HWP;
  const int p = m - bimg * HWP;
  const int h = p / WWD;
  const int w = p - h * WWD;
  const int baseA = (bimg * CC) * HWP + h * WWD + w;
  const int lane = tid & 63;
  const int wid = tid >> 6;
  const int wr = wid >> 1;
  const int wc = wid & 1;
  const int frow = lane & 15;
  const int kg = lane >> 4;
  f32x4 acc[4][4];
  const f32x4 zero = {0.0f, 0.0f, 0.0f, 0.0f};
#pragma unroll
  for (int i = 0; i < 4; ++i)
#pragma unroll
    for (int j = 0; j < 4; ++j) acc[i][j] = zero;
  for (int r = 0; r < 9; ++r) {
    const int dh = r / 3 - 1;
    const int dw = r - (r / 3) * 3 - 1;
    const int hh = h + dh;
    const int ww2 = w + dw;
    const bool valid = ((unsigned)hh < (unsigned)HH) && ((unsigned)ww2 < (unsigned)WWD);
    const int aoff2 = baseA + dh * WWD + dw + half * 16 * HWP;
    for (int c0 = 0; c0 < CC; c0 += 32) {
      __syncthreads();
      {
        const float* src = x + aoff2 + c0 * HWP;
        us8 v0, v1;
#pragma unroll
        for (int i = 0; i < 8; ++i) {
          float f0 = valid ? src[i * HWP] : 0.0f;
          float f1 = valid ? src[(i + 8) * HWP] : 0.0f;
          v0[i] = f2bf(f0);
          v1[i] = f2bf(f1);
        }
        *reinterpret_cast<us8*>(&Asm2[mi][half * 16]) = v0;
        *reinterpret_cast<us8*>(&Asm2[mi][half * 16 + 8]) = v1;
      }
      {
        us8 v0, v1;
#pragma unroll
        for (int i = 0; i < 8; ++i) {
          int cc2 = c0 + half * 16 + i;
          v0[i] = f2bf(Wf[(cc2 * 9 + r) * FF + mi]);
          v1[i] = f2bf(Wf[((cc2 + 8) * 9 + r) * FF + mi]);
        }
        *reinterpret_cast<us8*>(&Bsm2[mi][half * 16]) = v0;
        *reinterpret_cast<us8*>(&Bsm2[mi][half * 16 + 8]) = v1;
      }
      __syncthreads();
      bf16x8 af[4], bfr[4];
#pragma unroll
      for (int i = 0; i < 4; ++i)
        af[i] = *reinterpret_cast<const bf16x8*>(&Asm2[wr * 64 + i * 16 + frow][kg * 8]);
#pragma unroll
      for (int j = 0; j < 4; ++j)
        bfr[j] = *reinterpret_cast<const bf16x8*>(&Bsm2[wc * 64 + j * 16 + frow][kg * 8]);
#pragma unroll
      for (int i = 0; i < 4; ++i)
#pragma unroll
        for (int j = 0; j < 4; ++j)
          acc[i][j] = __builtin_amdgcn_mfma_f32_16x16x32_bf16(af[i], bfr[j], acc[i][j], 0, 0, 0);
    }
  }
#pragma unroll
  for (int j = 0; j < 4; ++j) {
    const int col = wc * 64 + j * 16 + frow;
    const float thr = 1.0f - Di[col];
#pragma unroll
    for (int i = 0; i < 4; ++i) {
      const int rbase = m0 + wr * 64 + i * 16 + kg * 4;
#pragma unroll
      for (int qq = 0; qq < 4; ++qq) {
        float v = acc[i][j][qq] + thr;
        out[(size_t)(rbase + qq) * FF + col] = fminf(v, 1.0f);
      }
    }
  }
}

extern "C" void kernel_launch(void* const* d_in, const int* in_sizes, int n_in,
                              void* d_out, int out_size, void* d_ws, size_t ws_size,
                              hipStream_t stream) {
  const float* tj = (const float*)d_in[0];
  const float* W = (const float*)d_in[1];
  const float* Di = (const float*)d_in[2];
  float* out = (float*)d_out;

  const size_t wt_bytes = (size_t)NSTEP * 512 * 16;  // 294912
  unsigned short* Wt = (unsigned short*)d_ws;

  bool fast = (ws_size >= wt_bytes);
  if (fast) {
    prep_w_kernel<<<72, 256, 0, stream>>>(W, Wt);
    spiking_conv_main<<<448, 256, 0, stream>>>(tj, Wt, Di, out);
    if (hipGetLastError() != hipSuccess) fast = false;
  }
  if (!fast) {
    spiking_conv_fallback<<<100352 / 128, 256, 0, stream>>>(tj, W, Di, out);
  }
}

// Round 13
// 69.948 us; speedup vs baseline: 1.1951x; 1.1951x over previous
//
#include <hip/hip_runtime.h>

// SpikingConv2D: y = conv3x3_same(tj, W) + (1 - D_i[0,f]); out = min(y, 1.0), NHWC fp32.
// R12 = R1 (best-proven main: 128px x 128f tile, BK=128/tap, 64 MFMA/barrier-pair,
// global_load_lds w/ pre-swizzled source, xp prepass) + three deltas:
//  1) ASM LIVENESS PIN: after loading the 8 fragments of each kk sub-step, an empty
//     asm ties all 8 (32 VGPRs) live -> scheduler MUST complete all 8 ds_read_b128
//     before the 16-MFMA burst; forbids the 4-reg-reuse serialized schedule that
//     capped R1/R6/R9 at VGPR<=128 and MfmaUtil ~20% (readout: VGPR_Count).
//  2) No occupancy hint: __launch_bounds__(256) only.
//  3) XCD-bijective block swizzle: 784 = 98 x 8.

#define BZ 32
#define CC 128
#define HH 56
#define WWD 56
#define HWP 3136
#define FF 128
#define KT 9
#define PH 58
#define PW 58
#define MTOT 100352
#define BM 128

typedef __attribute__((ext_vector_type(8))) __bf16 bf16x8;
typedef __attribute__((ext_vector_type(4))) float f32x4;
typedef __attribute__((ext_vector_type(8))) unsigned short us8;
typedef __attribute__((ext_vector_type(4))) float flt4;

__device__ __forceinline__ unsigned short f2bf(float f) {
  unsigned int u = __float_as_uint(f);
  unsigned int r = (u + 0x7FFFu + ((u >> 16) & 1u)) >> 16;
  return (unsigned short)r;
}

#define GLOAD_LDS16(g, l)                                                              \
  __builtin_amdgcn_global_load_lds((const __attribute__((address_space(1))) void*)(g), \
                                   (__attribute__((address_space(3))) void*)(l), 16, 0, 0)

// ---- W repack: [k=c*9+r][f] fp32 -> Wt[r][f][c'] bf16, c' = c ^ ((f&7)<<3) ----
__global__ void prep_w_kernel(const float* __restrict__ W, unsigned short* __restrict__ Wt,
                              int swz) {
  int idx = blockIdx.x * 256 + threadIdx.x;
  if (idx >= KT * FF * CC) return;
  int r = idx >> 14;
  int rem = idx & 16383;
  int f = rem >> 7;
  int c = rem & 127;
  int cs = swz ? (c ^ ((f & 7) << 3)) : c;
  Wt[(r * FF + f) * CC + cs] = f2bf(W[(c * KT + r) * FF + f]);
}

// ---- image prepass: x NCHW f32 -> xp padded NHWC bf16 [B][58][58][128] ----
__global__ __launch_bounds__(256) void prep_x_kernel(const float* __restrict__ x,
                                                     unsigned short* __restrict__ xp) {
  const int blk = blockIdx.x;
  const int b = blk / PH;
  const int ph = blk - b * PH;
  const int tid = threadIdx.x;
  unsigned short* dst = xp + (size_t)(b * PH + ph) * PW * CC;

  if (ph == 0 || ph == PH - 1) {
    us8 z;
#pragma unroll
    for (int k = 0; k < 8; ++k) z[k] = 0;
    for (int i = tid; i < PW * CC / 8; i += 256) reinterpret_cast<us8*>(dst)[i] = z;
    return;
  }

  __shared__ float sm[CC][57];
  const int h = ph - 1;
  {
    const int c = tid >> 1;
    const int half = tid & 1;
    const float* src = x + ((size_t)(b * CC + c)) * HWP + h * WWD + half * 28;
#pragma unroll
    for (int k = 0; k < 7; ++k) {
      flt4 v = *reinterpret_cast<const flt4*>(src + k * 4);
      sm[c][half * 28 + k * 4 + 0] = v[0];
      sm[c][half * 28 + k * 4 + 1] = v[1];
      sm[c][half * 28 + k * 4 + 2] = v[2];
      sm[c][half * 28 + k * 4 + 3] = v[3];
    }
  }
  __syncthreads();
  for (int i = tid; i < PW * 16; i += 256) {
    const int ww = i >> 4;
    const int cg = i & 15;
    us8 v;
    if (ww == 0 || ww == PW - 1) {
#pragma unroll
      for (int k = 0; k < 8; ++k) v[k] = 0;
    } else {
      const int w = ww - 1;
#pragma unroll
      for (int k = 0; k < 8; ++k) v[k] = f2bf(sm[cg * 8 + k][w]);
    }
    reinterpret_cast<us8*>(dst)[i] = v;
  }
}

// ---- main implicit-GEMM conv kernel ----
__global__ __launch_bounds__(256) void spiking_conv_main(
    const unsigned short* __restrict__ xp, const unsigned short* __restrict__ Wt,
    const float* __restrict__ Di, float* __restrict__ out) {
  __shared__ unsigned short Asm[BM * CC];  // 32 KB, linear dest, swizzled content
  __shared__ unsigned short Bsm[FF * CC];  // 32 KB

  // XCD-bijective swizzle: 784 blocks = 98 per XCD
  const int bid = blockIdx.x;
  const int wg = (bid & 7) * 98 + (bid >> 3);
  const int m0 = wg * BM;

  const int tid = threadIdx.x;
  const int lane = tid & 63;
  const int wv = tid >> 6;
  const int wr = wv >> 1, wc = wv & 1;
  const int frow = lane & 15, kg = lane >> 4;

  // --- per-thread staging source offsets (elements) ---
  int aoff[8];
#pragma unroll
  for (int t = 0; t < 8; ++t) {
    const int row = wv * 32 + t * 4 + (lane >> 4);
    const int m = m0 + row;
    const int b = m / HWP;
    const int p = m - b * HWP;
    const int h = p / WWD;
    const int w = p - h * WWD;
    const int chunk = (lane & 15) ^ (row & 7);  // inverse-swizzled source chunk
    aoff[t] = ((b * PH + h + 1) * PW + (w + 1)) * CC + chunk * 8;
  }
  const unsigned short* wsrc = Wt + wv * 4096 + lane * 8;

  f32x4 acc[4][4];
  const f32x4 zero = {0.0f, 0.0f, 0.0f, 0.0f};
#pragma unroll
  for (int i = 0; i < 4; ++i)
#pragma unroll
    for (int j = 0; j < 4; ++j) acc[i][j] = zero;

  for (int r = 0; r < KT; ++r) {
    const int dh = r / 3 - 1;
    const int dw = r - (r / 3) * 3 - 1;
    const int tapoff = (dh * PW + dw) * CC;
    __syncthreads();  // prior frag reads done before overwrite
#pragma unroll
    for (int t = 0; t < 8; ++t)
      GLOAD_LDS16(xp + aoff[t] + tapoff, Asm + wv * 4096 + t * 512);
#pragma unroll
    for (int t = 0; t < 8; ++t)
      GLOAD_LDS16(wsrc + r * (FF * CC) + t * 512, Bsm + wv * 4096 + t * 512);
    __syncthreads();  // includes vmcnt(0) drain

#pragma unroll
    for (int kk = 0; kk < 4; ++kk) {
      bf16x8 af[4], bfr[4];
#pragma unroll
      for (int i = 0; i < 4; ++i) {
        const int rowA = wr * 64 + i * 16 + frow;
        const int colb = (kk * 64 + kg * 16) ^ ((rowA & 7) << 4);
        af[i] = *reinterpret_cast<const bf16x8*>(
            reinterpret_cast<const char*>(Asm) + rowA * 256 + colb);
      }
#pragma unroll
      for (int j = 0; j < 4; ++j) {
        const int rowB = wc * 64 + j * 16 + frow;
        const int colb = (kk * 64 + kg * 16) ^ ((rowB & 7) << 4);
        bfr[j] = *reinterpret_cast<const bf16x8*>(
            reinterpret_cast<const char*>(Bsm) + rowB * 256 + colb);
      }
      // LIVENESS PIN: all 8 fragments (32 VGPRs) must be materialized here ->
      // the 8 ds_read_b128 complete before the MFMA burst; no reuse-serialization.
      asm volatile("" : "+v"(af[0]), "+v"(af[1]), "+v"(af[2]), "+v"(af[3]),
                        "+v"(bfr[0]), "+v"(bfr[1]), "+v"(bfr[2]), "+v"(bfr[3]));
#pragma unroll
      for (int i = 0; i < 4; ++i)
#pragma unroll
        for (int j = 0; j < 4; ++j)
          acc[i][j] = __builtin_amdgcn_mfma_f32_16x16x32_bf16(af[i], bfr[j], acc[i][j], 0, 0, 0);
    }
  }

  // ---- epilogue: + (1 - D_i[f]), clamp 1.0, NHWC fp32 ----
#pragma unroll
  for (int j = 0; j < 4; ++j) {
    const int col = wc * 64 + j * 16 + frow;
    const float thr = 1.0f - Di[col];
#pragma unroll
    for (int i = 0; i < 4; ++i) {
      const int rbase = m0 + wr * 64 + i * 16 + kg * 4;
#pragma unroll
      for (int q = 0; q < 4; ++q) {
        float v = acc[i][j][q] + thr;
        out[(size_t)(rbase + q) * FF + col] = fminf(v, 1.0f);
      }
    }
  }
}

// ---- fallback (reads W directly; used only if ws too small) ----
__global__ __launch_bounds__(256) void spiking_conv_fallback(
    const float* __restrict__ x, const float* __restrict__ Wf,
    const float* __restrict__ Di, float* __restrict__ out) {
  __shared__ unsigned short Asm2[128][32];
  __shared__ unsigned short Bsm2[128][32];
  const int tid = threadIdx.x;
  const int m0 = blockIdx.x * 128;
  const int mi = tid & 127;
  const int half = tid >> 7;
  const int m = m0 + mi;
  const int bimg = m / HWP;
  const int p = m - bimg * HWP;
  const int h = p / WWD;
  const int w = p - h * WWD;
  const int baseA = (bimg * CC) * HWP + h * WWD + w;
  const int lane = tid & 63;
  const int wid = tid >> 6;
  const int wr = wid >> 1;
  const int wc = wid & 1;
  const int frow = lane & 15;
  const int kg = lane >> 4;
  f32x4 acc[4][4];
  const f32x4 zero = {0.0f, 0.0f, 0.0f, 0.0f};
#pragma unroll
  for (int i = 0; i < 4; ++i)
#pragma unroll
    for (int j = 0; j < 4; ++j) acc[i][j] = zero;
  for (int r = 0; r < 9; ++r) {
    const int dh = r / 3 - 1;
    const int dw = r - (r / 3) * 3 - 1;
    const int hh = h + dh;
    const int ww2 = w + dw;
    const bool valid = ((unsigned)hh < (unsigned)HH) && ((unsigned)ww2 < (unsigned)WWD);
    const int aoff2 = baseA + dh * WWD + dw + half * 16 * HWP;
    for (int c0 = 0; c0 < CC; c0 += 32) {
      __syncthreads();
      {
        const float* src = x + aoff2 + c0 * HWP;
        us8 v0, v1;
#pragma unroll
        for (int i = 0; i < 8; ++i) {
          float f0 = valid ? src[i * HWP] : 0.0f;
          float f1 = valid ? src[(i + 8) * HWP] : 0.0f;
          v0[i] = f2bf(f0);
          v1[i] = f2bf(f1);
        }
        *reinterpret_cast<us8*>(&Asm2[mi][half * 16]) = v0;
        *reinterpret_cast<us8*>(&Asm2[mi][half * 16 + 8]) = v1;
      }
      {
        us8 v0, v1;
#pragma unroll
        for (int i = 0; i < 8; ++i) {
          int cc2 = c0 + half * 16 + i;
          v0[i] = f2bf(Wf[(cc2 * 9 + r) * FF + mi]);
          v1[i] = f2bf(Wf[((cc2 + 8) * 9 + r) * FF + mi]);
        }
        *reinterpret_cast<us8*>(&Bsm2[mi][half * 16]) = v0;
        *reinterpret_cast<us8*>(&Bsm2[mi][half * 16 + 8]) = v1;
      }
      __syncthreads();
      bf16x8 af[4], bfr[4];
#pragma unroll
      for (int i = 0; i < 4; ++i)
        af[i] = *reinterpret_cast<const bf16x8*>(&Asm2[wr * 64 + i * 16 + frow][kg * 8]);
#pragma unroll
      for (int j = 0; j < 4; ++j)
        bfr[j] = *reinterpret_cast<const bf16x8*>(&Bsm2[wc * 64 + j * 16 + frow][kg * 8]);
#pragma unroll
      for (int i = 0; i < 4; ++i)
#pragma unroll
        for (int j = 0; j < 4; ++j)
          acc[i][j] = __builtin_amdgcn_mfma_f32_16x16x32_bf16(af[i], bfr[j], acc[i][j], 0, 0, 0);
    }
  }
#pragma unroll
  for (int j = 0; j < 4; ++j) {
    const int col = wc * 64 + j * 16 + frow;
    const float thr = 1.0f - Di[col];
#pragma unroll
    for (int i = 0; i < 4; ++i) {
      const int rbase = m0 + wr * 64 + i * 16 + kg * 4;
#pragma unroll
      for (int q = 0; q < 4; ++q) {
        float v = acc[i][j][q] + thr;
        out[(size_t)(rbase + q) * FF + col] = fminf(v, 1.0f);
      }
    }
  }
}

extern "C" void kernel_launch(void* const* d_in, const int* in_sizes, int n_in,
                              void* d_out, int out_size, void* d_ws, size_t ws_size,
                              hipStream_t stream) {
  const float* tj = (const float*)d_in[0];
  const float* W = (const float*)d_in[1];
  const float* Di = (const float*)d_in[2];
  float* out = (float*)d_out;

  const size_t wt_bytes = (size_t)KT * FF * CC * 2;               // 294912
  const size_t xp_bytes = (size_t)BZ * PH * PW * CC * 2;          // 27557888
  unsigned short* Wt = (unsigned short*)d_ws;
  unsigned short* xp = (unsigned short*)((char*)d_ws + wt_bytes);

  bool fast = (ws_size >= wt_bytes + xp_bytes);
  if (fast) {
    prep_w_kernel<<<(KT * FF * CC + 255) / 256, 256, 0, stream>>>(W, Wt, 1);
    prep_x_kernel<<<BZ * PH, 256, 0, stream>>>(tj, xp);
    spiking_conv_main<<<MTOT / BM, 256, 0, stream>>>(xp, Wt, Di, out);
    if (hipGetLastError() != hipSuccess) fast = false;
  }
  if (!fast) {
    spiking_conv_fallback<<<100352 / 128, 256, 0, stream>>>(tj, W, Di, out);
  }
}